// Round 8
// baseline (338.051 us; speedup 1.0000x reference)
//
#include <hip/hip_runtime.h>
#include <cstdint>

// Int8 OPT attention block: B=2,T=2048,D=2048,H=32,HD=64
#define A_PROJ 3e-4f
#define A_QK   2e-5f
#define A_PV   1e-2f
#define A_OUT  1e-4f

#define NB 2
#define NT 2048
#define ND 2048
#define NH 32
#define NHD 64
#define NM (NB*NT)   // 4096 = B*T rows

typedef int v4i __attribute__((ext_vector_type(4)));

__device__ __forceinline__ int8_t sat8(float y) {
  float r = rintf(y);                      // half-to-even == np.round
  r = fminf(fmaxf(r, -128.f), 127.f);
  return (int8_t)(int)r;
}

// raw v_exp_f32: D = 2^x (device builtin; __exp2f collides with glibc macros)
__device__ __forceinline__ float exp2_fast(float x) {
  return __builtin_amdgcn_exp2f(x);
}

// async global->LDS, 16B/lane; LDS dest = wave-uniform base + lane*16
__device__ __forceinline__ void gl2lds16(const int8_t* g, int8_t* l) {
  __builtin_amdgcn_global_load_lds(
      (const __attribute__((address_space(1))) void*)g,
      (__attribute__((address_space(3))) void*)l, 16, 0, 0);
}

// pack 4 float low-bytes into one u32: bytes [b0,b1,b2,b3] = low bytes of f0..f3
__device__ __forceinline__ uint32_t pack_lo4(float f0, float f1, float f2, float f3) {
  uint32_t u0 = __float_as_uint(f0), u1 = __float_as_uint(f1);
  uint32_t u2 = __float_as_uint(f2), u3 = __float_as_uint(f3);
  uint32_t lo = __builtin_amdgcn_perm(u1, u0, 0x04000400u);  // [f0.b0, f1.b0, x, x]
  uint32_t hi = __builtin_amdgcn_perm(u3, u2, 0x04000400u);  // [f2.b0, f3.b0, x, x]
  return __builtin_amdgcn_perm(hi, lo, 0x05040100u);         // [f0,f1,f2,f3] low bytes
}

// ---------------- fused pack: int32 -> int8 for X + 4 weights ----------------
#define NWW (ND*ND/4)      // 1048576 words = 2^20
__global__ void pack_all(const int* __restrict__ X,
                         const int* __restrict__ W0, const int* __restrict__ W1,
                         const int* __restrict__ W2, const int* __restrict__ W3,
                         int8_t* __restrict__ dX, int8_t* __restrict__ dW0,
                         int8_t* __restrict__ dW1, int8_t* __restrict__ dW2,
                         int8_t* __restrict__ dW3) {
  int i = blockIdx.x * blockDim.x + threadIdx.x;
  const int nx = NM*ND/4;
  const int* src; int8_t* dst; int off;
  if (i < nx) { src = X; dst = dX; off = i; }
  else {
    int j = i - nx;
    int r = j >> 20;            // NWW = 2^20
    off = j & (NWW - 1);
    src = (r == 0) ? W0 : (r == 1) ? W1 : (r == 2) ? W2 : W3;
    dst = (r == 0) ? dW0 : (r == 1) ? dW1 : (r == 2) ? dW2 : dW3;
  }
  int4 v = ((const int4*)src)[off];
  uint32_t p = (uint32_t)(v.x & 255) | ((uint32_t)(v.y & 255) << 8) |
               ((uint32_t)(v.z & 255) << 16) | ((uint32_t)(v.w & 255) << 24);
  ((uint32_t*)dst)[off] = p;
}

// ---------------- QKV projection: C = sat8(A_PROJ * X @ W^T + bias) ----------------
// R14: 256x256 tile, BK=64, 512 threads (8 waves, 2M x 4N, wave-tile 128x64).
// Why: at 128^2 the per-step compute (~300-400cy) cannot cover HBM-miss latency
// (~900cy, FETCH 61.6MB >> 20MB ideal => L2 thrash), so every barrier's vmcnt(0)
// drain exposes latency regardless of prefetch depth (R12 null, R13 regression).
// At 256^2 one K-step is ~1300cy of MFMA+LDS work > HBM latency: 1-deep prefetch
// + single __syncthreads per step is self-covering. LDS-read bytes/op -40%
// (wave-tile 128x64). LDS 2x32KB dbuf; 1 block/CU (8 waves) - low occupancy is
// expected (HK 256^2 pattern). Chunk-XOR swizzle unchanged (0 conflicts).
// z=0 -> Qh[b][h][t][hd], z=1 -> Kh[b][h][t][hd], z=2 -> Vt[b][h][hd][t]
__global__ __launch_bounds__(512, 1) void gemm_qkv(
    const int8_t* __restrict__ X,
    const int8_t* __restrict__ Wq, const int8_t* __restrict__ Wk, const int8_t* __restrict__ Wv,
    const int* __restrict__ bq, const int* __restrict__ bk, const int* __restrict__ bv,
    int8_t* __restrict__ Qh, int8_t* __restrict__ Kh, int8_t* __restrict__ Vt)
{
  __shared__ __align__(16) int8_t As[2][256][64];   // stored chunk = logical ^ ((row>>1)&3)
  __shared__ __align__(16) int8_t Bs[2][256][64];
  const int z = blockIdx.z;
  const int8_t* W  = (z == 0) ? Wq : ((z == 1) ? Wk : Wv);
  const int* bias  = (z == 0) ? bq : ((z == 1) ? bk : bv);
  const int m0 = blockIdx.x * 256, n0 = blockIdx.y * 256;
  const int tid = threadIdx.x, lane = tid & 63, wave = tid >> 6;   // wave 0..7
  const int wm = wave >> 2, wn = wave & 3;        // 2M x 4N wave grid
  const int l15 = lane & 15, quad = lane >> 4;

  const int srow = lane >> 2;                               // staging row within 16-block
  const int scol = (((lane & 3) ^ ((lane >> 3) & 3)) * 16); // swizzled logical chunk
  const int rqcol = (quad ^ ((l15 >> 1) & 3)) * 16;         // frag-read stored chunk

  // staging: 4 gl2lds per wave per K-step (A 16KB + B 16KB = 32 x 1KB row-blocks)
  const int8_t* srcp[4];
  int8_t* dstp[4];
  srcp[0] = &X[(size_t)(m0 +       wave*16 + srow) * ND + scol]; dstp[0] = &As[0][      wave*16][0];
  srcp[1] = &X[(size_t)(m0 + 128 + wave*16 + srow) * ND + scol]; dstp[1] = &As[0][128 + wave*16][0];
  srcp[2] = &W[(size_t)(n0 +       wave*16 + srow) * ND + scol]; dstp[2] = &Bs[0][      wave*16][0];
  srcp[3] = &W[(size_t)(n0 + 128 + wave*16 + srow) * ND + scol]; dstp[3] = &Bs[0][128 + wave*16][0];

  v4i acc[8][4];
  const v4i vzero = {0, 0, 0, 0};
  #pragma unroll
  for (int i = 0; i < 8; ++i)
    #pragma unroll
    for (int j = 0; j < 4; ++j) acc[i][j] = vzero;

  // prologue: stage K-tile 0 into buf 0
  #pragma unroll
  for (int j = 0; j < 4; ++j) gl2lds16(srcp[j], dstp[j]);
  __syncthreads();

  int cur = 0;
  const int NK = ND / 64;                         // 32 K-steps
  for (int t = 0; t < NK; ++t) {
    if (t + 1 < NK) {
      const int boff = (cur ^ 1) * 16384;         // 256*64
      const int goff = (t + 1) * 64;
      #pragma unroll
      for (int j = 0; j < 4; ++j) gl2lds16(srcp[j] + goff, dstp[j] + boff);
    }
    const int8_t* Ab = &As[cur][0][0];
    const int8_t* Bb = &Bs[cur][0][0];
    v4i b[4];
    #pragma unroll
    for (int nt = 0; nt < 4; ++nt)
      b[nt] = *(const v4i*)(Bb + (wn*64 + nt*16 + l15) * 64 + rqcol);
    #pragma unroll
    for (int mt = 0; mt < 8; ++mt) {
      v4i a = *(const v4i*)(Ab + (wm*128 + mt*16 + l15) * 64 + rqcol);
      #pragma unroll
      for (int nt = 0; nt < 4; ++nt)
        acc[mt][nt] = __builtin_amdgcn_mfma_i32_16x16x64_i8(a, b[nt], acc[mt][nt], 0, 0, 0);
    }
    __syncthreads();
    cur ^= 1;
  }

  float bf[4];
  #pragma unroll
  for (int nt = 0; nt < 4; ++nt) bf[nt] = (float)bias[n0 + wn*64 + nt*16 + l15];

  if (z == 2) {
    // Vt[b][h][hd][t]: t = m-dir; quad*4+r are 4 consecutive t -> pack u32
    #pragma unroll
    for (int mt = 0; mt < 8; ++mt)
      #pragma unroll
      for (int nt = 0; nt < 4; ++nt) {
        int tbase = (m0 + wm*128 + mt*16 + quad*4) & (NT - 1);
        int bb = (m0 + wm*128) >> 11;
        int n = n0 + wn*64 + nt*16 + l15;
        int hh = n >> 6, hd = n & (NHD - 1);
        uint32_t pk = 0;
        #pragma unroll
        for (int r = 0; r < 4; ++r) {
          uint32_t q = (uint32_t)(uint8_t)sat8(A_PROJ * (float)acc[mt][nt][r] + bf[nt]);
          pk |= q << (8 * r);
        }
        size_t bh = (size_t)bb * NH + hh;
        *(uint32_t*)&Vt[(bh * NHD + hd) * NT + tbase] = pk;
      }
  } else {
    int8_t* O = (z == 0) ? Qh : Kh;
    #pragma unroll
    for (int mt = 0; mt < 8; ++mt)
      #pragma unroll
      for (int nt = 0; nt < 4; ++nt)
        #pragma unroll
        for (int r = 0; r < 4; ++r) {
          int m = m0 + wm*128 + mt*16 + quad*4 + r;    // C/D: row = quad*4+reg
          int n = n0 + wn*64 + nt*16 + l15;            //      col = lane&15
          int8_t q = sat8(A_PROJ * (float)acc[mt][nt][r] + bf[nt]);
          int bb = m >> 11, t = m & (NT - 1);
          int hh = n >> 6, hd = n & (NHD - 1);
          size_t bh = (size_t)bb * NH + hh;
          O[(bh * NT + t) * NHD + hd] = q;
        }
  }
}

// ---------------- fused causal attention (v8: prefetch-dbuf, 128t x 64s) ----------------
// R11 (verified win): block = ONE 128-row t-tile, 8 waves x 16 t-rows; s-loop in
// 64-wide steps; waves 0-3 stage next K, 4-7 stage next V into buf^1, compute
// from buf, ONE __syncthreads -> stage latency hides under compute. lsum is
// wave-local; no cross-group combine. Balanced bx->t-tile permutation per bh>>4.
__global__ __launch_bounds__(512, 8) void attn_fused(
    const int8_t* __restrict__ Qh, const int8_t* __restrict__ Kh, const int8_t* __restrict__ Vt,
    int8_t* __restrict__ AO)
{
  __shared__ __align__(16) int8_t Ksd[2][64][64];     // stored chunk = logical ^ ((row>>1)&3)
  __shared__ __align__(16) int8_t Vsd[2][64][64];     // same swizzle family
  __shared__ __align__(16) uint32_t Ps32[8][16][20];  // per-wave P (u32-packed, +pad)

  const int bx = blockIdx.x;           // 0..15
  const int bh = blockIdx.y;           // 0..63
  const int tid = threadIdx.x, lane = tid & 63, wave = tid >> 6;
  const int l15 = lane & 15, quad = lane >> 4;
  const v4i vzero = {0, 0, 0, 0};
  const float MAGIC = 12582912.0f;    // 1.5*2^23: low byte of fmaf(e,linv,MAGIC) = rne(e*linv)
  const float C2 = 2.8853900817779268e-05f;  // A_QK * log2(e): exp(A_QK x) = exp2(C2 x)

  // balanced bx -> t-tile permutation (sum of steps per strided-CU set == 68)
  const int jg = bh >> 4;
  const int x = (jg == 0) ? bx : (jg == 1) ? (15 - bx)
              : (jg == 2) ? ((bx + 8) & 15) : ((7 - bx) & 15);

  const int8_t* Qp = Qh + (size_t)bh * NT * NHD;
  const int8_t* Kp = Kh + (size_t)bh * NT * NHD;
  const int8_t* Vp = Vt + (size_t)bh * NHD * NT;
  const int bb = bh >> 5, hhead = bh & (NH - 1);

  const int t0 = x * 128;
  const int nsteps = 2 * x + 2;        // s-range covered: [0, t0+128)
  const int tw = t0 + wave * 16;       // wave's min t
  const int tme = tw + l15;            // lane's t row (mask compare)

  const int strow = lane >> 2;                                // staging row in 16-block
  const int stcol = (((lane & 3) ^ ((lane >> 3) & 3)) * 16);  // pre-swizzled source chunk
  const int fcol  = (quad ^ ((l15 >> 1) & 3)) * 16;           // frag-read stored chunk

  v4i qf = *(const v4i*)&Qp[(size_t)(tw + l15) * NHD + quad * 16];

  // ---- pass 1: l = sum_s exp(score); bounded scores -> no max subtraction
  float ls0 = 0.f, ls1 = 0.f, ls2 = 0.f, ls3 = 0.f;
  if (wave < 4)
    gl2lds16(&Kp[(size_t)(0 + wave*16 + strow) * NHD + stcol], &Ksd[0][wave*16][0]);
  __syncthreads();
  int cur = 0;
  for (int st = 0; st < nsteps; ++st) {
    if (st + 1 < nsteps && wave < 4)
      gl2lds16(&Kp[(size_t)((st+1)*64 + wave*16 + strow) * NHD + stcol],
               &Ksd[cur ^ 1][wave*16][0]);
    const int s0 = st * 64;
    if (s0 <= tw + 15) {                     // not fully masked for this wave
      v4i kf[4];
      #pragma unroll
      for (int mt = 0; mt < 4; ++mt) kf[mt] = *(const v4i*)&Ksd[cur][mt*16 + l15][fcol];
      if (s0 + 63 <= tw) {                   // fully valid
        #pragma unroll
        for (int mt = 0; mt < 4; ++mt) {
          v4i sa = __builtin_amdgcn_mfma_i32_16x16x64_i8(kf[mt], qf, vzero, 0, 0, 0);
          ls0 += exp2_fast(C2 * (float)sa[0]);
          ls1 += exp2_fast(C2 * (float)sa[1]);
          ls2 += exp2_fast(C2 * (float)sa[2]);
          ls3 += exp2_fast(C2 * (float)sa[3]);
        }
      } else {                               // diagonal-crossing: per-elem mask
        #pragma unroll
        for (int mt = 0; mt < 4; ++mt) {
          v4i sa = __builtin_amdgcn_mfma_i32_16x16x64_i8(kf[mt], qf, vzero, 0, 0, 0);
          const int sb = s0 + mt*16 + quad*4;
          ls0 += (sb + 0 <= tme) ? exp2_fast(C2 * (float)sa[0]) : 0.f;
          ls1 += (sb + 1 <= tme) ? exp2_fast(C2 * (float)sa[1]) : 0.f;
          ls2 += (sb + 2 <= tme) ? exp2_fast(C2 * (float)sa[2]) : 0.f;
          ls3 += (sb + 3 <= tme) ? exp2_fast(C2 * (float)sa[3]) : 0.f;
        }
      }
    }
    __syncthreads();
    cur ^= 1;
  }
  float lsum = (ls0 + ls1) + (ls2 + ls3);
  lsum += __shfl_xor(lsum, 16, 64);   // reduce over quads (same l15 = same t)
  lsum += __shfl_xor(lsum, 32, 64);
  const float linv = 127.0f / lsum;

  // ---- pass 2: p_i8 = rne(127*e/l) via magic trick; PV int8 MFMA accumulate
  v4i accv[4];
  #pragma unroll
  for (int jj = 0; jj < 4; ++jj) accv[jj] = vzero;

  if (wave < 4)
    gl2lds16(&Kp[(size_t)(0 + wave*16 + strow) * NHD + stcol], &Ksd[0][wave*16][0]);
  else
    gl2lds16(&Vp[(size_t)((wave-4)*16 + strow) * NT + 0 + stcol], &Vsd[0][(wave-4)*16][0]);
  __syncthreads();
  cur = 0;
  for (int st = 0; st < nsteps; ++st) {
    if (st + 1 < nsteps) {
      if (wave < 4)
        gl2lds16(&Kp[(size_t)((st+1)*64 + wave*16 + strow) * NHD + stcol],
                 &Ksd[cur ^ 1][wave*16][0]);
      else
        gl2lds16(&Vp[(size_t)((wave-4)*16 + strow) * NT + (st+1)*64 + stcol],
                 &Vsd[cur ^ 1][(wave-4)*16][0]);
    }
    const int s0 = st * 64;
    if (s0 <= tw + 15) {
      v4i kf[4];
      #pragma unroll
      for (int mt = 0; mt < 4; ++mt) kf[mt] = *(const v4i*)&Ksd[cur][mt*16 + l15][fcol];
      if (s0 + 63 <= tw) {
        #pragma unroll
        for (int mt = 0; mt < 4; ++mt) {
          v4i sa = __builtin_amdgcn_mfma_i32_16x16x64_i8(kf[mt], qf, vzero, 0, 0, 0);
          float f0 = fmaf(exp2_fast(C2 * (float)sa[0]), linv, MAGIC);
          float f1 = fmaf(exp2_fast(C2 * (float)sa[1]), linv, MAGIC);
          float f2 = fmaf(exp2_fast(C2 * (float)sa[2]), linv, MAGIC);
          float f3 = fmaf(exp2_fast(C2 * (float)sa[3]), linv, MAGIC);
          Ps32[wave][l15][mt*4 + quad] = pack_lo4(f0, f1, f2, f3);
        }
      } else {
        #pragma unroll
        for (int mt = 0; mt < 4; ++mt) {
          v4i sa = __builtin_amdgcn_mfma_i32_16x16x64_i8(kf[mt], qf, vzero, 0, 0, 0);
          const int sb = s0 + mt*16 + quad*4;
          float e0 = (sb + 0 <= tme) ? exp2_fast(C2 * (float)sa[0]) : 0.f;
          float e1 = (sb + 1 <= tme) ? exp2_fast(C2 * (float)sa[1]) : 0.f;
          float e2 = (sb + 2 <= tme) ? exp2_fast(C2 * (float)sa[2]) : 0.f;
          float e3 = (sb + 3 <= tme) ? exp2_fast(C2 * (float)sa[3]) : 0.f;
          Ps32[wave][l15][mt*4 + quad] =
              pack_lo4(fmaf(e0, linv, MAGIC), fmaf(e1, linv, MAGIC),
                       fmaf(e2, linv, MAGIC), fmaf(e3, linv, MAGIC));
        }
      }
      // wave-private LDS RAW: same-wave DS ordering + compiler lgkmcnt — no barrier
      v4i ap = *(const v4i*)&Ps32[wave][l15][quad*4];
      #pragma unroll
      for (int nt2 = 0; nt2 < 4; ++nt2) {
        v4i bvv = *(const v4i*)&Vsd[cur][nt2*16 + l15][fcol];
        accv[nt2] = __builtin_amdgcn_mfma_i32_16x16x64_i8(ap, bvv, accv[nt2], 0, 0, 0);
      }
    }
    __syncthreads();
    cur ^= 1;
  }

  // epilogue: AO[b][t][h*64+d];  C/D: row(quad*4+r)=t-local, col(l15)=d-local
  #pragma unroll
  for (int nt2 = 0; nt2 < 4; ++nt2)
    #pragma unroll
    for (int r = 0; r < 4; ++r) {
      int t = tw + quad*4 + r;
      int d = nt2*16 + l15;
      AO[((size_t)bb * NT + t) * ND + hhead * NHD + d] = sat8(A_PV * (float)accv[nt2][r]);
    }
}

// ---------------- out projection: out = A_OUT * AO @ Wo^T + bo (fp32) ----------------
// R12 structure (2-buffer prefetch, 1 barrier/step) — R13's 3-buffer reverted.
__global__ __launch_bounds__(256) void gemm_out(
    const int8_t* __restrict__ X, const int8_t* __restrict__ W,
    const float* __restrict__ bo, float* __restrict__ out)
{
  __shared__ __align__(16) int8_t As[2][128][64];
  __shared__ __align__(16) int8_t Bs[2][128][64];
  const int m0 = blockIdx.x * 128, n0 = blockIdx.y * 128;
  const int tid = threadIdx.x, lane = tid & 63, wave = tid >> 6;
  const int wm = wave >> 1, wn = wave & 1;
  const int l15 = lane & 15, quad = lane >> 4;
  const int srow = lane >> 2;
  const int scol = (((lane & 3) ^ ((lane >> 3) & 3)) * 16);
  const int rqcol = (quad ^ ((l15 >> 1) & 3)) * 16;

  const int8_t* srcp[4];
  int8_t* dstp[4];
  #pragma unroll
  for (int j = 0; j < 4; ++j) {
    int slot = j * 4 + wave;
    int rblk = slot & 7;
    int row = rblk * 16 + srow;
    if (slot < 8) { srcp[j] = &X[(size_t)(m0 + row) * ND + scol]; dstp[j] = &As[0][rblk*16][0]; }
    else          { srcp[j] = &W[(size_t)(n0 + row) * ND + scol]; dstp[j] = &Bs[0][rblk*16][0]; }
  }

  v4i acc[4][4];
  const v4i vzero = {0, 0, 0, 0};
  #pragma unroll
  for (int i = 0; i < 4; ++i)
    #pragma unroll
    for (int j = 0; j < 4; ++j) acc[i][j] = vzero;

  #pragma unroll
  for (int j = 0; j < 4; ++j) gl2lds16(srcp[j], dstp[j]);
  __syncthreads();

  int cur = 0;
  for (int k0 = 64; k0 <= ND; k0 += 64) {
    if (k0 < ND) {
      const int boff = (cur ^ 1) * 8192;
      #pragma unroll
      for (int j = 0; j < 4; ++j) gl2lds16(srcp[j] + k0, dstp[j] + boff);
    }
    v4i a[4], b[4];
    #pragma unroll
    for (int mt = 0; mt < 4; ++mt) a[mt] = *(const v4i*)&As[cur][wm*64 + mt*16 + l15][rqcol];
    #pragma unroll
    for (int nt = 0; nt < 4; ++nt) b[nt] = *(const v4i*)&Bs[cur][wn*64 + nt*16 + l15][rqcol];
    #pragma unroll
    for (int mt = 0; mt < 4; ++mt)
      #pragma unroll
      for (int nt = 0; nt < 4; ++nt)
        acc[mt][nt] = __builtin_amdgcn_mfma_i32_16x16x64_i8(a[mt], b[nt], acc[mt][nt], 0, 0, 0);
    __syncthreads();
    cur ^= 1;
  }

  float bf[4];
  #pragma unroll
  for (int nt = 0; nt < 4; ++nt) bf[nt] = bo[n0 + wn*64 + nt*16 + l15];

  #pragma unroll
  for (int mt = 0; mt < 4; ++mt)
    #pragma unroll
    for (int nt = 0; nt < 4; ++nt)
      #pragma unroll
      for (int r = 0; r < 4; ++r) {
        int m = m0 + wm*64 + mt*16 + quad*4 + r;
        int n = n0 + wn*64 + nt*16 + l15;
        out[(size_t)m * ND + n] = A_OUT * (float)acc[mt][nt][r] + bf[nt];
      }
}

extern "C" void kernel_launch(void* const* d_in, const int* in_sizes, int n_in,
                              void* d_out, int out_size, void* d_ws, size_t ws_size,
                              hipStream_t stream)
{
  const int*   hs  = (const int*)d_in[0];
  // d_in[1] = attention_mask: causal triu(-1e9) — applied structurally (s>t => p=0)
  const int*   Wq  = (const int*)d_in[2];
  const int*   bq  = (const int*)d_in[3];
  const int*   Wk  = (const int*)d_in[4];
  const int*   bkb = (const int*)d_in[5];
  const int*   Wv  = (const int*)d_in[6];
  const int*   bvb = (const int*)d_in[7];
  const int*   Wo  = (const int*)d_in[8];
  const float* bo  = (const float*)d_in[9];
  float* out = (float*)d_out;

  char* ws = (char*)d_ws;
  const size_t SZ_X = (size_t)NM * ND;              // 8 MiB
  const size_t SZ_W = (size_t)ND * ND;              // 4 MiB
  const size_t SZ_H = (size_t)NB * NH * NT * NHD;   // 8 MiB
  int8_t* Xp  = (int8_t*)ws;           // reused as AO after qkv gemm completes
  int8_t* Wqp = (int8_t*)(ws + SZ_X);
  int8_t* Wkp = Wqp + SZ_W;
  int8_t* Wvp = Wkp + SZ_W;
  int8_t* Wop = Wvp + SZ_W;
  int8_t* Qh  = Wop + SZ_W;
  int8_t* Kh  = Qh + SZ_H;
  int8_t* Vt  = Kh + SZ_H;
  int8_t* AO  = Xp;                    // alias: total ws use ~50.4 MB

  const int ntot = (int)(SZ_X/4 + 4 * (SZ_W/4));
  pack_all<<<(ntot + 255) / 256, 256, 0, stream>>>(hs, Wq, Wk, Wv, Wo,
                                                   Xp, Wqp, Wkp, Wvp, Wop);

  gemm_qkv<<<dim3(NM/256, ND/256, 3), 512, 0, stream>>>(Xp, Wqp, Wkp, Wvp, bq, bkb, bvb, Qh, Kh, Vt);
  attn_fused<<<dim3(16, NB*NH), 512, 0, stream>>>(Qh, Kh, Vt, AO);
  gemm_out<<<dim3(NM/128, ND/128), 256, 0, stream>>>(AO, Wop, bo, out);
}

// Round 9
// 314.224 us; speedup vs baseline: 1.0758x; 1.0758x over previous
//
#include <hip/hip_runtime.h>
#include <cstdint>

// Int8 OPT attention block: B=2,T=2048,D=2048,H=32,HD=64
#define A_PROJ 3e-4f
#define A_QK   2e-5f
#define A_PV   1e-2f
#define A_OUT  1e-4f

#define NB 2
#define NT 2048
#define ND 2048
#define NH 32
#define NHD 64
#define NM (NB*NT)   // 4096 = B*T rows

typedef int v4i __attribute__((ext_vector_type(4)));

__device__ __forceinline__ int8_t sat8(float y) {
  float r = rintf(y);                      // half-to-even == np.round
  r = fminf(fmaxf(r, -128.f), 127.f);
  return (int8_t)(int)r;
}

// raw v_exp_f32: D = 2^x (device builtin; __exp2f collides with glibc macros)
__device__ __forceinline__ float exp2_fast(float x) {
  return __builtin_amdgcn_exp2f(x);
}

// async global->LDS, 16B/lane; LDS dest = wave-uniform base + lane*16
__device__ __forceinline__ void gl2lds16(const int8_t* g, int8_t* l) {
  __builtin_amdgcn_global_load_lds(
      (const __attribute__((address_space(1))) void*)g,
      (__attribute__((address_space(3))) void*)l, 16, 0, 0);
}

// pack 4 float low-bytes into one u32: bytes [b0,b1,b2,b3] = low bytes of f0..f3
__device__ __forceinline__ uint32_t pack_lo4(float f0, float f1, float f2, float f3) {
  uint32_t u0 = __float_as_uint(f0), u1 = __float_as_uint(f1);
  uint32_t u2 = __float_as_uint(f2), u3 = __float_as_uint(f3);
  uint32_t lo = __builtin_amdgcn_perm(u1, u0, 0x04000400u);  // [f0.b0, f1.b0, x, x]
  uint32_t hi = __builtin_amdgcn_perm(u3, u2, 0x04000400u);  // [f2.b0, f3.b0, x, x]
  return __builtin_amdgcn_perm(hi, lo, 0x05040100u);         // [f0,f1,f2,f3] low bytes
}

// XCD-region swizzle for a 32x16 tile grid: each of the 8 XCDs (lid%8, assuming
// round-robin dispatch, m157) owns a disjoint 8bx x 8by region -> per-XCD
// concurrent working set = 8 X-panels (2MB) + 8 W-panels (2MB) ~= L2 (4MB),
// instead of ~70MB of distinct panels (the 3x HBM re-fetch seen in FETCH_SIZE).
__device__ __forceinline__ void xcd_map(int lid, int& bx, int& by) {
  int xcd = lid & 7, j = lid >> 3;        // j in [0,64)
  bx = (xcd & 3) * 8 + (j & 7);           // [0,32)
  by = (xcd >> 2) * 8 + (j >> 3);         // [0,16)
}

// ---------------- fused pack: int32 -> int8 for X + 4 weights ----------------
#define NWW (ND*ND/4)      // 1048576 words = 2^20
__global__ void pack_all(const int* __restrict__ X,
                         const int* __restrict__ W0, const int* __restrict__ W1,
                         const int* __restrict__ W2, const int* __restrict__ W3,
                         int8_t* __restrict__ dX, int8_t* __restrict__ dW0,
                         int8_t* __restrict__ dW1, int8_t* __restrict__ dW2,
                         int8_t* __restrict__ dW3) {
  int i = blockIdx.x * blockDim.x + threadIdx.x;
  const int nx = NM*ND/4;
  const int* src; int8_t* dst; int off;
  if (i < nx) { src = X; dst = dX; off = i; }
  else {
    int j = i - nx;
    int r = j >> 20;            // NWW = 2^20
    off = j & (NWW - 1);
    src = (r == 0) ? W0 : (r == 1) ? W1 : (r == 2) ? W2 : W3;
    dst = (r == 0) ? dW0 : (r == 1) ? dW1 : (r == 2) ? dW2 : dW3;
  }
  int4 v = ((const int4*)src)[off];
  uint32_t p = (uint32_t)(v.x & 255) | ((uint32_t)(v.y & 255) << 8) |
               ((uint32_t)(v.z & 255) << 16) | ((uint32_t)(v.w & 255) << 24);
  ((uint32_t*)dst)[off] = p;
}

// ---------------- QKV projection: C = sat8(A_PROJ * X @ W^T + bias) ----------------
// R15: exact R12 structure (76.0us: BK=64 prefetch-dbuf, hoisted pointers,
// 1 barrier/step, 32KB LDS, 5 blocks/CU) + XCD-region swizzle. R13 (3-buf
// counted vmcnt) and R14 (256^2) both regressed by trading away cross-block
// TLP; the real limiter is L2/L3 thrash (FETCH 61.6MB vs 20MB inputs -> ~900cy
// staging latency). The swizzle keeps each XCD's panels L2-resident so the
// existing prefetch-under-compute covers the (now ~200cy) staging latency.
// z=0 -> Qh[b][h][t][hd], z=1 -> Kh[b][h][t][hd], z=2 -> Vt[b][h][hd][t]
__global__ __launch_bounds__(256) void gemm_qkv(
    const int8_t* __restrict__ X,
    const int8_t* __restrict__ Wq, const int8_t* __restrict__ Wk, const int8_t* __restrict__ Wv,
    const int* __restrict__ bq, const int* __restrict__ bk, const int* __restrict__ bv,
    int8_t* __restrict__ Qh, int8_t* __restrict__ Kh, int8_t* __restrict__ Vt)
{
  __shared__ __align__(16) int8_t As[2][128][64];   // stored chunk = logical ^ ((row>>1)&3)
  __shared__ __align__(16) int8_t Bs[2][128][64];
  const int z = blockIdx.z;
  const int8_t* W  = (z == 0) ? Wq : ((z == 1) ? Wk : Wv);
  const int* bias  = (z == 0) ? bq : ((z == 1) ? bk : bv);
  int bx, by;
  xcd_map(blockIdx.x + 32 * blockIdx.y, bx, by);
  const int m0 = bx * 128, n0 = by * 128;
  const int tid = threadIdx.x, lane = tid & 63, wave = tid >> 6;
  const int wm = wave >> 1, wn = wave & 1;
  const int l15 = lane & 15, quad = lane >> 4;

  const int srow = lane >> 2;                               // staging row within 16-block
  const int scol = (((lane & 3) ^ ((lane >> 3) & 3)) * 16); // swizzled logical chunk
  const int rqcol = (quad ^ ((l15 >> 1) & 3)) * 16;         // frag-read stored chunk

  // hoisted staging pointers: 16 slots of 16 rows (8 A + 8 B), 4 waves x 4 issues
  const int8_t* srcp[4];
  int8_t* dstp[4];
  #pragma unroll
  for (int j = 0; j < 4; ++j) {
    int slot = j * 4 + wave;          // 0..15
    int rblk = slot & 7;
    int row = rblk * 16 + srow;
    if (slot < 8) { srcp[j] = &X[(size_t)(m0 + row) * ND + scol]; dstp[j] = &As[0][rblk*16][0]; }
    else          { srcp[j] = &W[(size_t)(n0 + row) * ND + scol]; dstp[j] = &Bs[0][rblk*16][0]; }
  }

  v4i acc[4][4];
  const v4i vzero = {0, 0, 0, 0};
  #pragma unroll
  for (int i = 0; i < 4; ++i)
    #pragma unroll
    for (int j = 0; j < 4; ++j) acc[i][j] = vzero;

  // prologue: stage step 0 into buf 0
  #pragma unroll
  for (int j = 0; j < 4; ++j) gl2lds16(srcp[j], dstp[j]);
  __syncthreads();

  int cur = 0;
  for (int k0 = 64; k0 <= ND; k0 += 64) {       // 32 compute steps
    if (k0 < ND) {
      const int boff = (cur ^ 1) * 8192;        // As[1]/Bs[1] offset from [0]
      #pragma unroll
      for (int j = 0; j < 4; ++j) gl2lds16(srcp[j] + k0, dstp[j] + boff);
    }
    v4i a[4], b[4];
    #pragma unroll
    for (int mt = 0; mt < 4; ++mt) a[mt] = *(const v4i*)&As[cur][wm*64 + mt*16 + l15][rqcol];
    #pragma unroll
    for (int nt = 0; nt < 4; ++nt) b[nt] = *(const v4i*)&Bs[cur][wn*64 + nt*16 + l15][rqcol];
    #pragma unroll
    for (int mt = 0; mt < 4; ++mt)
      #pragma unroll
      for (int nt = 0; nt < 4; ++nt)
        acc[mt][nt] = __builtin_amdgcn_mfma_i32_16x16x64_i8(a[mt], b[nt], acc[mt][nt], 0, 0, 0);
    __syncthreads();
    cur ^= 1;
  }

  float bf[4];
  #pragma unroll
  for (int nt = 0; nt < 4; ++nt) bf[nt] = (float)bias[n0 + wn*64 + nt*16 + l15];

  if (z == 2) {
    // Vt[b][h][hd][t]: t = m-dir; quad*4+r are 4 consecutive t -> pack u32
    #pragma unroll
    for (int mt = 0; mt < 4; ++mt)
      #pragma unroll
      for (int nt = 0; nt < 4; ++nt) {
        int tbase = (m0 + wm*64 + mt*16 + quad*4) & (NT - 1);
        int bb = (m0 + wm*64) >> 11;
        int n = n0 + wn*64 + nt*16 + l15;
        int hh = n >> 6, hd = n & (NHD - 1);
        uint32_t pk = 0;
        #pragma unroll
        for (int r = 0; r < 4; ++r) {
          uint32_t q = (uint32_t)(uint8_t)sat8(A_PROJ * (float)acc[mt][nt][r] + bf[nt]);
          pk |= q << (8 * r);
        }
        size_t bh = (size_t)bb * NH + hh;
        *(uint32_t*)&Vt[(bh * NHD + hd) * NT + tbase] = pk;
      }
  } else {
    int8_t* O = (z == 0) ? Qh : Kh;
    #pragma unroll
    for (int mt = 0; mt < 4; ++mt)
      #pragma unroll
      for (int nt = 0; nt < 4; ++nt)
        #pragma unroll
        for (int r = 0; r < 4; ++r) {
          int m = m0 + wm*64 + mt*16 + quad*4 + r;     // C/D: row = quad*4+reg
          int n = n0 + wn*64 + nt*16 + l15;            //      col = lane&15
          int8_t q = sat8(A_PROJ * (float)acc[mt][nt][r] + bf[nt]);
          int bb = m >> 11, t = m & (NT - 1);
          int hh = n >> 6, hd = n & (NHD - 1);
          size_t bh = (size_t)bb * NH + hh;
          O[(bh * NT + t) * NHD + hd] = q;
        }
  }
}

// ---------------- fused causal attention (v8: prefetch-dbuf, 128t x 64s) ----------------
// R11 (verified win): block = ONE 128-row t-tile, 8 waves x 16 t-rows; s-loop in
// 64-wide steps; waves 0-3 stage next K, 4-7 stage next V into buf^1, compute
// from buf, ONE __syncthreads -> stage latency hides under compute. lsum is
// wave-local; no cross-group combine. Balanced bx->t-tile permutation per bh>>4.
__global__ __launch_bounds__(512, 8) void attn_fused(
    const int8_t* __restrict__ Qh, const int8_t* __restrict__ Kh, const int8_t* __restrict__ Vt,
    int8_t* __restrict__ AO)
{
  __shared__ __align__(16) int8_t Ksd[2][64][64];     // stored chunk = logical ^ ((row>>1)&3)
  __shared__ __align__(16) int8_t Vsd[2][64][64];     // same swizzle family
  __shared__ __align__(16) uint32_t Ps32[8][16][20];  // per-wave P (u32-packed, +pad)

  const int bx = blockIdx.x;           // 0..15
  const int bh = blockIdx.y;           // 0..63
  const int tid = threadIdx.x, lane = tid & 63, wave = tid >> 6;
  const int l15 = lane & 15, quad = lane >> 4;
  const v4i vzero = {0, 0, 0, 0};
  const float MAGIC = 12582912.0f;    // 1.5*2^23: low byte of fmaf(e,linv,MAGIC) = rne(e*linv)
  const float C2 = 2.8853900817779268e-05f;  // A_QK * log2(e): exp(A_QK x) = exp2(C2 x)

  // balanced bx -> t-tile permutation (sum of steps per strided-CU set == 68)
  const int jg = bh >> 4;
  const int x = (jg == 0) ? bx : (jg == 1) ? (15 - bx)
              : (jg == 2) ? ((bx + 8) & 15) : ((7 - bx) & 15);

  const int8_t* Qp = Qh + (size_t)bh * NT * NHD;
  const int8_t* Kp = Kh + (size_t)bh * NT * NHD;
  const int8_t* Vp = Vt + (size_t)bh * NHD * NT;
  const int bb = bh >> 5, hhead = bh & (NH - 1);

  const int t0 = x * 128;
  const int nsteps = 2 * x + 2;        // s-range covered: [0, t0+128)
  const int tw = t0 + wave * 16;       // wave's min t
  const int tme = tw + l15;            // lane's t row (mask compare)

  const int strow = lane >> 2;                                // staging row in 16-block
  const int stcol = (((lane & 3) ^ ((lane >> 3) & 3)) * 16);  // pre-swizzled source chunk
  const int fcol  = (quad ^ ((l15 >> 1) & 3)) * 16;           // frag-read stored chunk

  v4i qf = *(const v4i*)&Qp[(size_t)(tw + l15) * NHD + quad * 16];

  // ---- pass 1: l = sum_s exp(score); bounded scores -> no max subtraction
  float ls0 = 0.f, ls1 = 0.f, ls2 = 0.f, ls3 = 0.f;
  if (wave < 4)
    gl2lds16(&Kp[(size_t)(0 + wave*16 + strow) * NHD + stcol], &Ksd[0][wave*16][0]);
  __syncthreads();
  int cur = 0;
  for (int st = 0; st < nsteps; ++st) {
    if (st + 1 < nsteps && wave < 4)
      gl2lds16(&Kp[(size_t)((st+1)*64 + wave*16 + strow) * NHD + stcol],
               &Ksd[cur ^ 1][wave*16][0]);
    const int s0 = st * 64;
    if (s0 <= tw + 15) {                     // not fully masked for this wave
      v4i kf[4];
      #pragma unroll
      for (int mt = 0; mt < 4; ++mt) kf[mt] = *(const v4i*)&Ksd[cur][mt*16 + l15][fcol];
      if (s0 + 63 <= tw) {                   // fully valid
        #pragma unroll
        for (int mt = 0; mt < 4; ++mt) {
          v4i sa = __builtin_amdgcn_mfma_i32_16x16x64_i8(kf[mt], qf, vzero, 0, 0, 0);
          ls0 += exp2_fast(C2 * (float)sa[0]);
          ls1 += exp2_fast(C2 * (float)sa[1]);
          ls2 += exp2_fast(C2 * (float)sa[2]);
          ls3 += exp2_fast(C2 * (float)sa[3]);
        }
      } else {                               // diagonal-crossing: per-elem mask
        #pragma unroll
        for (int mt = 0; mt < 4; ++mt) {
          v4i sa = __builtin_amdgcn_mfma_i32_16x16x64_i8(kf[mt], qf, vzero, 0, 0, 0);
          const int sb = s0 + mt*16 + quad*4;
          ls0 += (sb + 0 <= tme) ? exp2_fast(C2 * (float)sa[0]) : 0.f;
          ls1 += (sb + 1 <= tme) ? exp2_fast(C2 * (float)sa[1]) : 0.f;
          ls2 += (sb + 2 <= tme) ? exp2_fast(C2 * (float)sa[2]) : 0.f;
          ls3 += (sb + 3 <= tme) ? exp2_fast(C2 * (float)sa[3]) : 0.f;
        }
      }
    }
    __syncthreads();
    cur ^= 1;
  }
  float lsum = (ls0 + ls1) + (ls2 + ls3);
  lsum += __shfl_xor(lsum, 16, 64);   // reduce over quads (same l15 = same t)
  lsum += __shfl_xor(lsum, 32, 64);
  const float linv = 127.0f / lsum;

  // ---- pass 2: p_i8 = rne(127*e/l) via magic trick; PV int8 MFMA accumulate
  v4i accv[4];
  #pragma unroll
  for (int jj = 0; jj < 4; ++jj) accv[jj] = vzero;

  if (wave < 4)
    gl2lds16(&Kp[(size_t)(0 + wave*16 + strow) * NHD + stcol], &Ksd[0][wave*16][0]);
  else
    gl2lds16(&Vp[(size_t)((wave-4)*16 + strow) * NT + 0 + stcol], &Vsd[0][(wave-4)*16][0]);
  __syncthreads();
  cur = 0;
  for (int st = 0; st < nsteps; ++st) {
    if (st + 1 < nsteps) {
      if (wave < 4)
        gl2lds16(&Kp[(size_t)((st+1)*64 + wave*16 + strow) * NHD + stcol],
                 &Ksd[cur ^ 1][wave*16][0]);
      else
        gl2lds16(&Vp[(size_t)((wave-4)*16 + strow) * NT + (st+1)*64 + stcol],
                 &Vsd[cur ^ 1][(wave-4)*16][0]);
    }
    const int s0 = st * 64;
    if (s0 <= tw + 15) {
      v4i kf[4];
      #pragma unroll
      for (int mt = 0; mt < 4; ++mt) kf[mt] = *(const v4i*)&Ksd[cur][mt*16 + l15][fcol];
      if (s0 + 63 <= tw) {
        #pragma unroll
        for (int mt = 0; mt < 4; ++mt) {
          v4i sa = __builtin_amdgcn_mfma_i32_16x16x64_i8(kf[mt], qf, vzero, 0, 0, 0);
          float f0 = fmaf(exp2_fast(C2 * (float)sa[0]), linv, MAGIC);
          float f1 = fmaf(exp2_fast(C2 * (float)sa[1]), linv, MAGIC);
          float f2 = fmaf(exp2_fast(C2 * (float)sa[2]), linv, MAGIC);
          float f3 = fmaf(exp2_fast(C2 * (float)sa[3]), linv, MAGIC);
          Ps32[wave][l15][mt*4 + quad] = pack_lo4(f0, f1, f2, f3);
        }
      } else {
        #pragma unroll
        for (int mt = 0; mt < 4; ++mt) {
          v4i sa = __builtin_amdgcn_mfma_i32_16x16x64_i8(kf[mt], qf, vzero, 0, 0, 0);
          const int sb = s0 + mt*16 + quad*4;
          float e0 = (sb + 0 <= tme) ? exp2_fast(C2 * (float)sa[0]) : 0.f;
          float e1 = (sb + 1 <= tme) ? exp2_fast(C2 * (float)sa[1]) : 0.f;
          float e2 = (sb + 2 <= tme) ? exp2_fast(C2 * (float)sa[2]) : 0.f;
          float e3 = (sb + 3 <= tme) ? exp2_fast(C2 * (float)sa[3]) : 0.f;
          Ps32[wave][l15][mt*4 + quad] =
              pack_lo4(fmaf(e0, linv, MAGIC), fmaf(e1, linv, MAGIC),
                       fmaf(e2, linv, MAGIC), fmaf(e3, linv, MAGIC));
        }
      }
      // wave-private LDS RAW: same-wave DS ordering + compiler lgkmcnt — no barrier
      v4i ap = *(const v4i*)&Ps32[wave][l15][quad*4];
      #pragma unroll
      for (int nt2 = 0; nt2 < 4; ++nt2) {
        v4i bvv = *(const v4i*)&Vsd[cur][nt2*16 + l15][fcol];
        accv[nt2] = __builtin_amdgcn_mfma_i32_16x16x64_i8(ap, bvv, accv[nt2], 0, 0, 0);
      }
    }
    __syncthreads();
    cur ^= 1;
  }

  // epilogue: AO[b][t][h*64+d];  C/D: row(quad*4+r)=t-local, col(l15)=d-local
  #pragma unroll
  for (int nt2 = 0; nt2 < 4; ++nt2)
    #pragma unroll
    for (int r = 0; r < 4; ++r) {
      int t = tw + quad*4 + r;
      int d = nt2*16 + l15;
      AO[((size_t)bb * NT + t) * ND + hhead * NHD + d] = sat8(A_PV * (float)accv[nt2][r]);
    }
}

// ---------------- out projection: out = A_OUT * AO @ Wo^T + bo (fp32) ----------------
// R12 structure (2-buffer prefetch, 1 barrier/step) + XCD-region swizzle.
__global__ __launch_bounds__(256) void gemm_out(
    const int8_t* __restrict__ X, const int8_t* __restrict__ W,
    const float* __restrict__ bo, float* __restrict__ out)
{
  __shared__ __align__(16) int8_t As[2][128][64];
  __shared__ __align__(16) int8_t Bs[2][128][64];
  int bx, by;
  xcd_map(blockIdx.x + 32 * blockIdx.y, bx, by);
  const int m0 = bx * 128, n0 = by * 128;
  const int tid = threadIdx.x, lane = tid & 63, wave = tid >> 6;
  const int wm = wave >> 1, wn = wave & 1;
  const int l15 = lane & 15, quad = lane >> 4;
  const int srow = lane >> 2;
  const int scol = (((lane & 3) ^ ((lane >> 3) & 3)) * 16);
  const int rqcol = (quad ^ ((l15 >> 1) & 3)) * 16;

  const int8_t* srcp[4];
  int8_t* dstp[4];
  #pragma unroll
  for (int j = 0; j < 4; ++j) {
    int slot = j * 4 + wave;
    int rblk = slot & 7;
    int row = rblk * 16 + srow;
    if (slot < 8) { srcp[j] = &X[(size_t)(m0 + row) * ND + scol]; dstp[j] = &As[0][rblk*16][0]; }
    else          { srcp[j] = &W[(size_t)(n0 + row) * ND + scol]; dstp[j] = &Bs[0][rblk*16][0]; }
  }

  v4i acc[4][4];
  const v4i vzero = {0, 0, 0, 0};
  #pragma unroll
  for (int i = 0; i < 4; ++i)
    #pragma unroll
    for (int j = 0; j < 4; ++j) acc[i][j] = vzero;

  #pragma unroll
  for (int j = 0; j < 4; ++j) gl2lds16(srcp[j], dstp[j]);
  __syncthreads();

  int cur = 0;
  for (int k0 = 64; k0 <= ND; k0 += 64) {
    if (k0 < ND) {
      const int boff = (cur ^ 1) * 8192;
      #pragma unroll
      for (int j = 0; j < 4; ++j) gl2lds16(srcp[j] + k0, dstp[j] + boff);
    }
    v4i a[4], b[4];
    #pragma unroll
    for (int mt = 0; mt < 4; ++mt) a[mt] = *(const v4i*)&As[cur][wm*64 + mt*16 + l15][rqcol];
    #pragma unroll
    for (int nt = 0; nt < 4; ++nt) b[nt] = *(const v4i*)&Bs[cur][wn*64 + nt*16 + l15][rqcol];
    #pragma unroll
    for (int mt = 0; mt < 4; ++mt)
      #pragma unroll
      for (int nt = 0; nt < 4; ++nt)
        acc[mt][nt] = __builtin_amdgcn_mfma_i32_16x16x64_i8(a[mt], b[nt], acc[mt][nt], 0, 0, 0);
    __syncthreads();
    cur ^= 1;
  }

  float bf[4];
  #pragma unroll
  for (int nt = 0; nt < 4; ++nt) bf[nt] = bo[n0 + wn*64 + nt*16 + l15];

  #pragma unroll
  for (int mt = 0; mt < 4; ++mt)
    #pragma unroll
    for (int nt = 0; nt < 4; ++nt)
      #pragma unroll
      for (int r = 0; r < 4; ++r) {
        int m = m0 + wm*64 + mt*16 + quad*4 + r;
        int n = n0 + wn*64 + nt*16 + l15;
        out[(size_t)m * ND + n] = A_OUT * (float)acc[mt][nt][r] + bf[nt];
      }
}

extern "C" void kernel_launch(void* const* d_in, const int* in_sizes, int n_in,
                              void* d_out, int out_size, void* d_ws, size_t ws_size,
                              hipStream_t stream)
{
  const int*   hs  = (const int*)d_in[0];
  // d_in[1] = attention_mask: causal triu(-1e9) — applied structurally (s>t => p=0)
  const int*   Wq  = (const int*)d_in[2];
  const int*   bq  = (const int*)d_in[3];
  const int*   Wk  = (const int*)d_in[4];
  const int*   bkb = (const int*)d_in[5];
  const int*   Wv  = (const int*)d_in[6];
  const int*   bvb = (const int*)d_in[7];
  const int*   Wo  = (const int*)d_in[8];
  const float* bo  = (const float*)d_in[9];
  float* out = (float*)d_out;

  char* ws = (char*)d_ws;
  const size_t SZ_X = (size_t)NM * ND;              // 8 MiB
  const size_t SZ_W = (size_t)ND * ND;              // 4 MiB
  const size_t SZ_H = (size_t)NB * NH * NT * NHD;   // 8 MiB
  int8_t* Xp  = (int8_t*)ws;           // reused as AO after qkv gemm completes
  int8_t* Wqp = (int8_t*)(ws + SZ_X);
  int8_t* Wkp = Wqp + SZ_W;
  int8_t* Wvp = Wkp + SZ_W;
  int8_t* Wop = Wvp + SZ_W;
  int8_t* Qh  = Wop + SZ_W;
  int8_t* Kh  = Qh + SZ_H;
  int8_t* Vt  = Kh + SZ_H;
  int8_t* AO  = Xp;                    // alias: total ws use ~50.4 MB

  const int ntot = (int)(SZ_X/4 + 4 * (SZ_W/4));
  pack_all<<<(ntot + 255) / 256, 256, 0, stream>>>(hs, Wq, Wk, Wv, Wo,
                                                   Xp, Wqp, Wkp, Wvp, Wop);

  gemm_qkv<<<dim3(NM/128, ND/128, 3), 256, 0, stream>>>(Xp, Wqp, Wkp, Wvp, bq, bkb, bvb, Qh, Kh, Vt);
  attn_fused<<<dim3(16, NB*NH), 512, 0, stream>>>(Qh, Kh, Vt, AO);
  gemm_out<<<dim3(NM/128, ND/128), 256, 0, stream>>>(AO, Wop, bo, out);
}

// Round 10
// 304.449 us; speedup vs baseline: 1.1104x; 1.0321x over previous
//
#include <hip/hip_runtime.h>
#include <cstdint>

// Int8 OPT attention block: B=2,T=2048,D=2048,H=32,HD=64
#define A_PROJ 3e-4f
#define A_QK   2e-5f
#define A_PV   1e-2f
#define A_OUT  1e-4f

#define NB 2
#define NT 2048
#define ND 2048
#define NH 32
#define NHD 64
#define NM (NB*NT)   // 4096 = B*T rows

typedef int v4i __attribute__((ext_vector_type(4)));

__device__ __forceinline__ int8_t sat8(float y) {
  float r = rintf(y);                      // half-to-even == np.round
  r = fminf(fmaxf(r, -128.f), 127.f);
  return (int8_t)(int)r;
}

// raw v_exp_f32: D = 2^x (device builtin; __exp2f collides with glibc macros)
__device__ __forceinline__ float exp2_fast(float x) {
  return __builtin_amdgcn_exp2f(x);
}

// async global->LDS, 16B/lane; LDS dest = wave-uniform base + lane*16
__device__ __forceinline__ void gl2lds16(const int8_t* g, int8_t* l) {
  __builtin_amdgcn_global_load_lds(
      (const __attribute__((address_space(1))) void*)g,
      (__attribute__((address_space(3))) void*)l, 16, 0, 0);
}

// pack 4 float low-bytes into one u32: bytes [b0,b1,b2,b3] = low bytes of f0..f3
__device__ __forceinline__ uint32_t pack_lo4(float f0, float f1, float f2, float f3) {
  uint32_t u0 = __float_as_uint(f0), u1 = __float_as_uint(f1);
  uint32_t u2 = __float_as_uint(f2), u3 = __float_as_uint(f3);
  uint32_t lo = __builtin_amdgcn_perm(u1, u0, 0x04000400u);  // [f0.b0, f1.b0, x, x]
  uint32_t hi = __builtin_amdgcn_perm(u3, u2, 0x04000400u);  // [f2.b0, f3.b0, x, x]
  return __builtin_amdgcn_perm(hi, lo, 0x05040100u);         // [f0,f1,f2,f3] low bytes
}

// XCD-region swizzle for a 32x16 tile grid (R15: FETCH -20% verified).
__device__ __forceinline__ void xcd_map(int lid, int& bx, int& by) {
  int xcd = lid & 7, j = lid >> 3;        // j in [0,64)
  bx = (xcd & 3) * 8 + (j & 7);           // [0,32)
  by = (xcd >> 2) * 8 + (j >> 3);         // [0,16)
}

// ---------------- fused pack: int32 -> int8 for X + 4 weights ----------------
#define NWW (ND*ND/4)      // 1048576 words = 2^20
__global__ void pack_all(const int* __restrict__ X,
                         const int* __restrict__ W0, const int* __restrict__ W1,
                         const int* __restrict__ W2, const int* __restrict__ W3,
                         int8_t* __restrict__ dX, int8_t* __restrict__ dW0,
                         int8_t* __restrict__ dW1, int8_t* __restrict__ dW2,
                         int8_t* __restrict__ dW3) {
  int i = blockIdx.x * blockDim.x + threadIdx.x;
  const int nx = NM*ND/4;
  const int* src; int8_t* dst; int off;
  if (i < nx) { src = X; dst = dX; off = i; }
  else {
    int j = i - nx;
    int r = j >> 20;            // NWW = 2^20
    off = j & (NWW - 1);
    src = (r == 0) ? W0 : (r == 1) ? W1 : (r == 2) ? W2 : W3;
    dst = (r == 0) ? dW0 : (r == 1) ? dW1 : (r == 2) ? dW2 : dW3;
  }
  int4 v = ((const int4*)src)[off];
  uint32_t p = (uint32_t)(v.x & 255) | ((uint32_t)(v.y & 255) << 8) |
               ((uint32_t)(v.z & 255) << 16) | ((uint32_t)(v.w & 255) << 24);
  ((uint32_t*)dst)[off] = p;
}

// ---------------- QKV projection: all 3 outputs per block ----------------
// R16: one block computes Q,K,V for its (bx,by) tile. X panel staged ONCE
// (was 3x across z-blocks); per K-step each wave runs 48 MFMAs (~960cy) vs
// 900cy staging latency -> the R12 issue-next/compute/__syncthreads schedule
// becomes self-covering (the vmcnt(0) drain finds the prefetch landed).
// R12-R15 were pinned at 74-76us because 16 MFMA/step (~320cy) < latency.
// LDS: S[2][4][128][64] = 64KB (plane 0 = X, 1-3 = Wq/Wk/Wv) -> 2 blocks/CU,
// grid 512 = exactly 2/CU. acc[3][4][4] v4i = 192 VGPR (b loaded singly to
// stay ~250 total). Chunk-XOR swizzle unchanged (0 conflicts). XCD swizzle kept.
__global__ __launch_bounds__(256, 2) void gemm_qkv(
    const int8_t* __restrict__ X,
    const int8_t* __restrict__ Wq, const int8_t* __restrict__ Wk, const int8_t* __restrict__ Wv,
    const int* __restrict__ bq, const int* __restrict__ bk, const int* __restrict__ bv,
    int8_t* __restrict__ Qh, int8_t* __restrict__ Kh, int8_t* __restrict__ Vt)
{
  __shared__ __align__(16) int8_t S[2][4][128][64];   // [buf][plane][row][chunk]
  int bx, by;
  xcd_map(blockIdx.x + 32 * blockIdx.y, bx, by);
  const int m0 = bx * 128, n0 = by * 128;
  const int tid = threadIdx.x, lane = tid & 63, wave = tid >> 6;
  const int wm = wave >> 1, wn = wave & 1;
  const int l15 = lane & 15, quad = lane >> 4;

  const int srow = lane >> 2;                               // staging row within 16-block
  const int scol = (((lane & 3) ^ ((lane >> 3) & 3)) * 16); // swizzled logical chunk
  const int rqcol = (quad ^ ((l15 >> 1) & 3)) * 16;         // frag-read stored chunk

  // staging: 32 slots of 16 rows (8 X + 8 Wq + 8 Wk + 8 Wv), 4 waves x 8 issues
  const int8_t* srcp[8];
  int8_t* dstp[8];
  #pragma unroll
  for (int j = 0; j < 8; ++j) {
    int slot = j * 4 + wave;          // 0..31
    int rblk = slot & 7;
    int sel  = slot >> 3;             // 0=X, 1=Wq, 2=Wk, 3=Wv
    int row  = rblk * 16 + srow;
    const int8_t* base = (sel == 0) ? &X[(size_t)(m0 + row) * ND]
                                    : (sel == 1) ? &Wq[(size_t)(n0 + row) * ND]
                                    : (sel == 2) ? &Wk[(size_t)(n0 + row) * ND]
                                                 : &Wv[(size_t)(n0 + row) * ND];
    srcp[j] = base + scol;
    dstp[j] = &S[0][sel][rblk * 16][0];
  }

  v4i acc[3][4][4];
  const v4i vzero = {0, 0, 0, 0};
  #pragma unroll
  for (int z = 0; z < 3; ++z)
    #pragma unroll
    for (int i = 0; i < 4; ++i)
      #pragma unroll
      for (int j = 0; j < 4; ++j) acc[z][i][j] = vzero;

  // prologue: stage step 0 into buf 0
  #pragma unroll
  for (int j = 0; j < 8; ++j) gl2lds16(srcp[j], dstp[j]);
  __syncthreads();

  int cur = 0;
  for (int k0 = 64; k0 <= ND; k0 += 64) {       // 32 compute steps
    if (k0 < ND) {
      const int boff = (cur ^ 1) * 32768;       // buffer stride = 4*128*64
      #pragma unroll
      for (int j = 0; j < 8; ++j) gl2lds16(srcp[j] + k0, dstp[j] + boff);
    }
    v4i a[4];
    #pragma unroll
    for (int mt = 0; mt < 4; ++mt)
      a[mt] = *(const v4i*)&S[cur][0][wm*64 + mt*16 + l15][rqcol];
    #pragma unroll
    for (int z = 0; z < 3; ++z)
      #pragma unroll
      for (int nt = 0; nt < 4; ++nt) {
        v4i b = *(const v4i*)&S[cur][1 + z][wn*64 + nt*16 + l15][rqcol];
        #pragma unroll
        for (int mt = 0; mt < 4; ++mt)
          acc[z][mt][nt] = __builtin_amdgcn_mfma_i32_16x16x64_i8(a[mt], b, acc[z][mt][nt], 0, 0, 0);
      }
    __syncthreads();
    cur ^= 1;
  }

  // epilogue: z=0 -> Qh, z=1 -> Kh, z=2 -> Vt (u32-packed)
  #pragma unroll
  for (int z = 0; z < 3; ++z) {
    const int* bias = (z == 0) ? bq : (z == 1) ? bk : bv;
    float bf[4];
    #pragma unroll
    for (int nt = 0; nt < 4; ++nt) bf[nt] = (float)bias[n0 + wn*64 + nt*16 + l15];
    if (z == 2) {
      #pragma unroll
      for (int mt = 0; mt < 4; ++mt)
        #pragma unroll
        for (int nt = 0; nt < 4; ++nt) {
          int tbase = (m0 + wm*64 + mt*16 + quad*4) & (NT - 1);
          int bb = (m0 + wm*64) >> 11;
          int n = n0 + wn*64 + nt*16 + l15;
          int hh = n >> 6, hd = n & (NHD - 1);
          uint32_t pk = 0;
          #pragma unroll
          for (int r = 0; r < 4; ++r) {
            uint32_t q = (uint32_t)(uint8_t)sat8(A_PROJ * (float)acc[z][mt][nt][r] + bf[nt]);
            pk |= q << (8 * r);
          }
          size_t bh = (size_t)bb * NH + hh;
          *(uint32_t*)&Vt[(bh * NHD + hd) * NT + tbase] = pk;
        }
    } else {
      int8_t* O = (z == 0) ? Qh : Kh;
      #pragma unroll
      for (int mt = 0; mt < 4; ++mt)
        #pragma unroll
        for (int nt = 0; nt < 4; ++nt)
          #pragma unroll
          for (int r = 0; r < 4; ++r) {
            int m = m0 + wm*64 + mt*16 + quad*4 + r;     // C/D: row = quad*4+reg
            int n = n0 + wn*64 + nt*16 + l15;            //      col = lane&15
            int8_t q = sat8(A_PROJ * (float)acc[z][mt][nt][r] + bf[nt]);
            int bb = m >> 11, t = m & (NT - 1);
            int hh = n >> 6, hd = n & (NHD - 1);
            size_t bh = (size_t)bb * NH + hh;
            O[(bh * NT + t) * NHD + hd] = q;
          }
    }
  }
}

// ---------------- fused causal attention (v8: prefetch-dbuf, 128t x 64s) ----------------
// R11 (verified win): block = ONE 128-row t-tile, 8 waves x 16 t-rows; s-loop in
// 64-wide steps; waves 0-3 stage next K, 4-7 stage next V into buf^1, compute
// from buf, ONE __syncthreads -> stage latency hides under compute. lsum is
// wave-local; no cross-group combine. Balanced bx->t-tile permutation per bh>>4.
__global__ __launch_bounds__(512, 8) void attn_fused(
    const int8_t* __restrict__ Qh, const int8_t* __restrict__ Kh, const int8_t* __restrict__ Vt,
    int8_t* __restrict__ AO)
{
  __shared__ __align__(16) int8_t Ksd[2][64][64];     // stored chunk = logical ^ ((row>>1)&3)
  __shared__ __align__(16) int8_t Vsd[2][64][64];     // same swizzle family
  __shared__ __align__(16) uint32_t Ps32[8][16][20];  // per-wave P (u32-packed, +pad)

  const int bx = blockIdx.x;           // 0..15
  const int bh = blockIdx.y;           // 0..63
  const int tid = threadIdx.x, lane = tid & 63, wave = tid >> 6;
  const int l15 = lane & 15, quad = lane >> 4;
  const v4i vzero = {0, 0, 0, 0};
  const float MAGIC = 12582912.0f;    // 1.5*2^23: low byte of fmaf(e,linv,MAGIC) = rne(e*linv)
  const float C2 = 2.8853900817779268e-05f;  // A_QK * log2(e): exp(A_QK x) = exp2(C2 x)

  // balanced bx -> t-tile permutation (sum of steps per strided-CU set == 68)
  const int jg = bh >> 4;
  const int x = (jg == 0) ? bx : (jg == 1) ? (15 - bx)
              : (jg == 2) ? ((bx + 8) & 15) : ((7 - bx) & 15);

  const int8_t* Qp = Qh + (size_t)bh * NT * NHD;
  const int8_t* Kp = Kh + (size_t)bh * NT * NHD;
  const int8_t* Vp = Vt + (size_t)bh * NHD * NT;
  const int bb = bh >> 5, hhead = bh & (NH - 1);

  const int t0 = x * 128;
  const int nsteps = 2 * x + 2;        // s-range covered: [0, t0+128)
  const int tw = t0 + wave * 16;       // wave's min t
  const int tme = tw + l15;            // lane's t row (mask compare)

  const int strow = lane >> 2;                                // staging row in 16-block
  const int stcol = (((lane & 3) ^ ((lane >> 3) & 3)) * 16);  // pre-swizzled source chunk
  const int fcol  = (quad ^ ((l15 >> 1) & 3)) * 16;           // frag-read stored chunk

  v4i qf = *(const v4i*)&Qp[(size_t)(tw + l15) * NHD + quad * 16];

  // ---- pass 1: l = sum_s exp(score); bounded scores -> no max subtraction
  float ls0 = 0.f, ls1 = 0.f, ls2 = 0.f, ls3 = 0.f;
  if (wave < 4)
    gl2lds16(&Kp[(size_t)(0 + wave*16 + strow) * NHD + stcol], &Ksd[0][wave*16][0]);
  __syncthreads();
  int cur = 0;
  for (int st = 0; st < nsteps; ++st) {
    if (st + 1 < nsteps && wave < 4)
      gl2lds16(&Kp[(size_t)((st+1)*64 + wave*16 + strow) * NHD + stcol],
               &Ksd[cur ^ 1][wave*16][0]);
    const int s0 = st * 64;
    if (s0 <= tw + 15) {                     // not fully masked for this wave
      v4i kf[4];
      #pragma unroll
      for (int mt = 0; mt < 4; ++mt) kf[mt] = *(const v4i*)&Ksd[cur][mt*16 + l15][fcol];
      if (s0 + 63 <= tw) {                   // fully valid
        #pragma unroll
        for (int mt = 0; mt < 4; ++mt) {
          v4i sa = __builtin_amdgcn_mfma_i32_16x16x64_i8(kf[mt], qf, vzero, 0, 0, 0);
          ls0 += exp2_fast(C2 * (float)sa[0]);
          ls1 += exp2_fast(C2 * (float)sa[1]);
          ls2 += exp2_fast(C2 * (float)sa[2]);
          ls3 += exp2_fast(C2 * (float)sa[3]);
        }
      } else {                               // diagonal-crossing: per-elem mask
        #pragma unroll
        for (int mt = 0; mt < 4; ++mt) {
          v4i sa = __builtin_amdgcn_mfma_i32_16x16x64_i8(kf[mt], qf, vzero, 0, 0, 0);
          const int sb = s0 + mt*16 + quad*4;
          ls0 += (sb + 0 <= tme) ? exp2_fast(C2 * (float)sa[0]) : 0.f;
          ls1 += (sb + 1 <= tme) ? exp2_fast(C2 * (float)sa[1]) : 0.f;
          ls2 += (sb + 2 <= tme) ? exp2_fast(C2 * (float)sa[2]) : 0.f;
          ls3 += (sb + 3 <= tme) ? exp2_fast(C2 * (float)sa[3]) : 0.f;
        }
      }
    }
    __syncthreads();
    cur ^= 1;
  }
  float lsum = (ls0 + ls1) + (ls2 + ls3);
  lsum += __shfl_xor(lsum, 16, 64);   // reduce over quads (same l15 = same t)
  lsum += __shfl_xor(lsum, 32, 64);
  const float linv = 127.0f / lsum;

  // ---- pass 2: p_i8 = rne(127*e/l) via magic trick; PV int8 MFMA accumulate
  v4i accv[4];
  #pragma unroll
  for (int jj = 0; jj < 4; ++jj) accv[jj] = vzero;

  if (wave < 4)
    gl2lds16(&Kp[(size_t)(0 + wave*16 + strow) * NHD + stcol], &Ksd[0][wave*16][0]);
  else
    gl2lds16(&Vp[(size_t)((wave-4)*16 + strow) * NT + 0 + stcol], &Vsd[0][(wave-4)*16][0]);
  __syncthreads();
  cur = 0;
  for (int st = 0; st < nsteps; ++st) {
    if (st + 1 < nsteps) {
      if (wave < 4)
        gl2lds16(&Kp[(size_t)((st+1)*64 + wave*16 + strow) * NHD + stcol],
                 &Ksd[cur ^ 1][wave*16][0]);
      else
        gl2lds16(&Vp[(size_t)((wave-4)*16 + strow) * NT + (st+1)*64 + stcol],
                 &Vsd[cur ^ 1][(wave-4)*16][0]);
    }
    const int s0 = st * 64;
    if (s0 <= tw + 15) {
      v4i kf[4];
      #pragma unroll
      for (int mt = 0; mt < 4; ++mt) kf[mt] = *(const v4i*)&Ksd[cur][mt*16 + l15][fcol];
      if (s0 + 63 <= tw) {
        #pragma unroll
        for (int mt = 0; mt < 4; ++mt) {
          v4i sa = __builtin_amdgcn_mfma_i32_16x16x64_i8(kf[mt], qf, vzero, 0, 0, 0);
          float f0 = fmaf(exp2_fast(C2 * (float)sa[0]), linv, MAGIC);
          float f1 = fmaf(exp2_fast(C2 * (float)sa[1]), linv, MAGIC);
          float f2 = fmaf(exp2_fast(C2 * (float)sa[2]), linv, MAGIC);
          float f3 = fmaf(exp2_fast(C2 * (float)sa[3]), linv, MAGIC);
          Ps32[wave][l15][mt*4 + quad] = pack_lo4(f0, f1, f2, f3);
        }
      } else {
        #pragma unroll
        for (int mt = 0; mt < 4; ++mt) {
          v4i sa = __builtin_amdgcn_mfma_i32_16x16x64_i8(kf[mt], qf, vzero, 0, 0, 0);
          const int sb = s0 + mt*16 + quad*4;
          float e0 = (sb + 0 <= tme) ? exp2_fast(C2 * (float)sa[0]) : 0.f;
          float e1 = (sb + 1 <= tme) ? exp2_fast(C2 * (float)sa[1]) : 0.f;
          float e2 = (sb + 2 <= tme) ? exp2_fast(C2 * (float)sa[2]) : 0.f;
          float e3 = (sb + 3 <= tme) ? exp2_fast(C2 * (float)sa[3]) : 0.f;
          Ps32[wave][l15][mt*4 + quad] =
              pack_lo4(fmaf(e0, linv, MAGIC), fmaf(e1, linv, MAGIC),
                       fmaf(e2, linv, MAGIC), fmaf(e3, linv, MAGIC));
        }
      }
      // wave-private LDS RAW: same-wave DS ordering + compiler lgkmcnt — no barrier
      v4i ap = *(const v4i*)&Ps32[wave][l15][quad*4];
      #pragma unroll
      for (int nt2 = 0; nt2 < 4; ++nt2) {
        v4i bvv = *(const v4i*)&Vsd[cur][nt2*16 + l15][fcol];
        accv[nt2] = __builtin_amdgcn_mfma_i32_16x16x64_i8(ap, bvv, accv[nt2], 0, 0, 0);
      }
    }
    __syncthreads();
    cur ^= 1;
  }

  // epilogue: AO[b][t][h*64+d];  C/D: row(quad*4+r)=t-local, col(l15)=d-local
  #pragma unroll
  for (int nt2 = 0; nt2 < 4; ++nt2)
    #pragma unroll
    for (int r = 0; r < 4; ++r) {
      int t = tw + quad*4 + r;
      int d = nt2*16 + l15;
      AO[((size_t)bb * NT + t) * ND + hhead * NHD + d] = sat8(A_PV * (float)accv[nt2][r]);
    }
}

// ---------------- out projection: out = A_OUT * AO @ Wo^T + bo (fp32) ----------------
// R12 structure (2-buffer prefetch, 1 barrier/step) + XCD-region swizzle.
__global__ __launch_bounds__(256) void gemm_out(
    const int8_t* __restrict__ X, const int8_t* __restrict__ W,
    const float* __restrict__ bo, float* __restrict__ out)
{
  __shared__ __align__(16) int8_t As[2][128][64];
  __shared__ __align__(16) int8_t Bs[2][128][64];
  int bx, by;
  xcd_map(blockIdx.x + 32 * blockIdx.y, bx, by);
  const int m0 = bx * 128, n0 = by * 128;
  const int tid = threadIdx.x, lane = tid & 63, wave = tid >> 6;
  const int wm = wave >> 1, wn = wave & 1;
  const int l15 = lane & 15, quad = lane >> 4;
  const int srow = lane >> 2;
  const int scol = (((lane & 3) ^ ((lane >> 3) & 3)) * 16);
  const int rqcol = (quad ^ ((l15 >> 1) & 3)) * 16;

  const int8_t* srcp[4];
  int8_t* dstp[4];
  #pragma unroll
  for (int j = 0; j < 4; ++j) {
    int slot = j * 4 + wave;
    int rblk = slot & 7;
    int row = rblk * 16 + srow;
    if (slot < 8) { srcp[j] = &X[(size_t)(m0 + row) * ND + scol]; dstp[j] = &As[0][rblk*16][0]; }
    else          { srcp[j] = &W[(size_t)(n0 + row) * ND + scol]; dstp[j] = &Bs[0][rblk*16][0]; }
  }

  v4i acc[4][4];
  const v4i vzero = {0, 0, 0, 0};
  #pragma unroll
  for (int i = 0; i < 4; ++i)
    #pragma unroll
    for (int j = 0; j < 4; ++j) acc[i][j] = vzero;

  #pragma unroll
  for (int j = 0; j < 4; ++j) gl2lds16(srcp[j], dstp[j]);
  __syncthreads();

  int cur = 0;
  for (int k0 = 64; k0 <= ND; k0 += 64) {
    if (k0 < ND) {
      const int boff = (cur ^ 1) * 8192;
      #pragma unroll
      for (int j = 0; j < 4; ++j) gl2lds16(srcp[j] + k0, dstp[j] + boff);
    }
    v4i a[4], b[4];
    #pragma unroll
    for (int mt = 0; mt < 4; ++mt) a[mt] = *(const v4i*)&As[cur][wm*64 + mt*16 + l15][rqcol];
    #pragma unroll
    for (int nt = 0; nt < 4; ++nt) b[nt] = *(const v4i*)&Bs[cur][wn*64 + nt*16 + l15][rqcol];
    #pragma unroll
    for (int mt = 0; mt < 4; ++mt)
      #pragma unroll
      for (int nt = 0; nt < 4; ++nt)
        acc[mt][nt] = __builtin_amdgcn_mfma_i32_16x16x64_i8(a[mt], b[nt], acc[mt][nt], 0, 0, 0);
    __syncthreads();
    cur ^= 1;
  }

  float bf[4];
  #pragma unroll
  for (int nt = 0; nt < 4; ++nt) bf[nt] = bo[n0 + wn*64 + nt*16 + l15];

  #pragma unroll
  for (int mt = 0; mt < 4; ++mt)
    #pragma unroll
    for (int nt = 0; nt < 4; ++nt)
      #pragma unroll
      for (int r = 0; r < 4; ++r) {
        int m = m0 + wm*64 + mt*16 + quad*4 + r;
        int n = n0 + wn*64 + nt*16 + l15;
        out[(size_t)m * ND + n] = A_OUT * (float)acc[mt][nt][r] + bf[nt];
      }
}

extern "C" void kernel_launch(void* const* d_in, const int* in_sizes, int n_in,
                              void* d_out, int out_size, void* d_ws, size_t ws_size,
                              hipStream_t stream)
{
  const int*   hs  = (const int*)d_in[0];
  // d_in[1] = attention_mask: causal triu(-1e9) — applied structurally (s>t => p=0)
  const int*   Wq  = (const int*)d_in[2];
  const int*   bq  = (const int*)d_in[3];
  const int*   Wk  = (const int*)d_in[4];
  const int*   bkb = (const int*)d_in[5];
  const int*   Wv  = (const int*)d_in[6];
  const int*   bvb = (const int*)d_in[7];
  const int*   Wo  = (const int*)d_in[8];
  const float* bo  = (const float*)d_in[9];
  float* out = (float*)d_out;

  char* ws = (char*)d_ws;
  const size_t SZ_X = (size_t)NM * ND;              // 8 MiB
  const size_t SZ_W = (size_t)ND * ND;              // 4 MiB
  const size_t SZ_H = (size_t)NB * NH * NT * NHD;   // 8 MiB
  int8_t* Xp  = (int8_t*)ws;           // reused as AO after qkv gemm completes
  int8_t* Wqp = (int8_t*)(ws + SZ_X);
  int8_t* Wkp = Wqp + SZ_W;
  int8_t* Wvp = Wkp + SZ_W;
  int8_t* Wop = Wvp + SZ_W;
  int8_t* Qh  = Wop + SZ_W;
  int8_t* Kh  = Qh + SZ_H;
  int8_t* Vt  = Kh + SZ_H;
  int8_t* AO  = Xp;                    // alias: total ws use ~50.4 MB

  const int ntot = (int)(SZ_X/4 + 4 * (SZ_W/4));
  pack_all<<<(ntot + 255) / 256, 256, 0, stream>>>(hs, Wq, Wk, Wv, Wo,
                                                   Xp, Wqp, Wkp, Wvp, Wop);

  gemm_qkv<<<dim3(32, 16), 256, 0, stream>>>(Xp, Wqp, Wkp, Wvp, bq, bkb, bvb, Qh, Kh, Vt);
  attn_fused<<<dim3(16, NB*NH), 512, 0, stream>>>(Qh, Kh, Vt, AO);
  gemm_out<<<dim3(NM/128, ND/128), 256, 0, stream>>>(AO, Wop, bo, out);
}